// Round 13
// baseline (212.369 us; speedup 1.0000x reference)
//
#include <hip/hip_runtime.h>

using u16 = unsigned short;
typedef float f32x4 __attribute__((ext_vector_type(4)));
typedef __bf16 bf16x8 __attribute__((ext_vector_type(8)));
typedef unsigned short u16x4 __attribute__((ext_vector_type(4)));
typedef unsigned short u16x8 __attribute__((ext_vector_type(8)));
typedef unsigned int u32x2 __attribute__((ext_vector_type(2)));

static constexpr float SC2 = 0.03125f * 1.44269504088896f; // (1/sqrt(1024)) * log2(e)

static __device__ __forceinline__ u16 f2bf(float f) {
  unsigned u = __builtin_bit_cast(unsigned, f);
  u += 0x7FFFu + ((u >> 16) & 1u);
  return (u16)(u >> 16);
}
static __device__ __forceinline__ float bf2f(u16 h) {
  unsigned u = ((unsigned)h) << 16;
  return __builtin_bit_cast(float, u);
}
static __device__ __forceinline__ unsigned cvt_pk(float lo, float hi) {
  unsigned r;
  asm("v_cvt_pk_bf16_f32 %0, %1, %2" : "=v"(r) : "v"(lo), "v"(hi));
  return r;
}

typedef __attribute__((address_space(3))) unsigned int lds_uint;
typedef __attribute__((address_space(1))) unsigned int g_uint;

static __device__ __forceinline__ void load_lds16(const u16* gp, const void* lp) {
  __builtin_amdgcn_global_load_lds((g_uint*)(unsigned long long)gp,
                                   (lds_uint*)(unsigned int)(unsigned long long)lp,
                                   16, 0, 0);
}

// ---------------- fused prep: casts + LDS-transpose relayouts, ONE dispatch ----------------
struct Prep {
  const float* src; const float* tgt;
  const float* w[3]; const float* W[3]; const float* ow;
  u16* src_bf; u16* tgt_bf; u16* w_bf[3]; u16* Wt[3]; u16* owT;
};
__global__ __launch_bounds__(256) void k_prep(Prep P) {
  __shared__ float tile[64][65];
  const int bid = blockIdx.x, t = threadIdx.x;
  if (bid < 16384) {
    const float* in = bid < 8192 ? P.src : P.tgt;
    u16* out = bid < 8192 ? P.src_bf : P.tgt_bf;
    int i = (bid & 8191) * 256 + t;
    f32x4 v = reinterpret_cast<const f32x4*>(in)[i];
    u16x4 o;
    o[0] = f2bf(v[0]); o[1] = f2bf(v[1]); o[2] = f2bf(v[2]); o[3] = f2bf(v[3]);
    reinterpret_cast<u16x4*>(out)[i] = o;
  } else if (bid < 19456) {
    int r = bid - 16384;
    int z = r >> 10;
    int i = (r & 1023) * 256 + t;
    f32x4 v = reinterpret_cast<const f32x4*>(P.w[z])[i];
    u16x4 o;
    o[0] = f2bf(v[0]); o[1] = f2bf(v[1]); o[2] = f2bf(v[2]); o[3] = f2bf(v[3]);
    reinterpret_cast<u16x4*>(P.w_bf[z])[i] = o;
  } else if (bid < 20224) {
    // W (H,1024,64) -> WQt[h*64+j][c]; 64x64 tile at (h, c0): contiguous 16KB read
    int r = bid - 19456;
    int z = r >> 8;
    int rr = r & 255;
    int h = rr >> 4, c0 = (rr & 15) << 6;
    const float* Wt_in = P.W[z] + (size_t)h * 65536 + (size_t)c0 * 64;
#pragma unroll
    for (int rep = 0; rep < 4; ++rep) {
      int i = rep * 256 + t;
      int cc = i >> 4, j4 = (i & 15) * 4;
      f32x4 v = *reinterpret_cast<const f32x4*>(Wt_in + cc * 64 + j4);
#pragma unroll
      for (int q = 0; q < 4; ++q) tile[cc][j4 + q] = v[q];
    }
    __syncthreads();
    u16* out = P.Wt[z];
#pragma unroll
    for (int rep = 0; rep < 2; ++rep) {
      int i = rep * 256 + t;
      int j = i >> 3, cc8 = (i & 7) * 8;
      u16x8 o;
#pragma unroll
      for (int q = 0; q < 8; ++q) o[q] = f2bf(tile[cc8 + q][j]);
      *reinterpret_cast<u16x8*>(out + (size_t)(h * 64 + j) * 1024 + c0 + cc8) = o;
    }
  } else {
    // ow (1024,1024) -> owT[n][k] = ow[k][n]; 64x64 tile at (k0, n0)
    int r = bid - 20224;
    int k0 = (r >> 4) << 6, n0 = (r & 15) << 6;
#pragma unroll
    for (int rep = 0; rep < 4; ++rep) {
      int i = rep * 256 + t;
      int kk = i >> 4, n4 = (i & 15) * 4;
      f32x4 v = *reinterpret_cast<const f32x4*>(P.ow + (size_t)(k0 + kk) * 1024 + n0 + n4);
#pragma unroll
      for (int q = 0; q < 4; ++q) tile[kk][n4 + q] = v[q];
    }
    __syncthreads();
#pragma unroll
    for (int rep = 0; rep < 2; ++rep) {
      int i = rep * 256 + t;
      int nn = i >> 3, kk8 = (i & 7) * 8;
      u16x8 o;
#pragma unroll
      for (int q = 0; q < 8; ++q) o[q] = f2bf(tile[kk8 + q][nn]);
      *reinterpret_cast<u16x8*>(P.owT + (size_t)(n0 + nn) * 1024 + k0 + kk8) = o;
    }
  }
}

// ---------------- bf16 GEMM, C[m][n] = scale * sum_k A[m][k]*Bt[n][k] ----------------
// m97-replica: 128x128 tile, BK=32, double-buffered (32KB LDS -> ~5 blocks/CU),
// issue-early staging, XCD-bijective swizzle (T1), G21 XOR swizzle adapted to
// 4-slot rows: sigma(row)=((row>>1)&3) -> reads hit each bank 2x (free, m136).
// mode 0: bf16 C[m][n]; mode 1: f32 C + bias; mode 2: bf16 vT[bh][d][kk].
struct GemmPtrs { const u16* A; const u16* B; void* C; float scale; int mode; };
struct Gemm3 { GemmPtrs g[3]; };

__global__ __launch_bounds__(256) void k_gemm_bt(Gemm3 P, int N, int K,
                                                 const float* __restrict__ bias) {
  const u16* A  = P.g[blockIdx.z].A;
  const u16* Bt = P.g[blockIdx.z].B;
  const float sc = P.g[blockIdx.z].scale;
  const int mode = P.g[blockIdx.z].mode;
  __shared__ u16 As[2][128 * 32];
  __shared__ u16 Bs[2][128 * 32];
  const int tid = threadIdx.x, lane = tid & 63, w = tid >> 6;
  const int swz = (blockIdx.x & 7) * (gridDim.x >> 3) + (blockIdx.x >> 3);
  const int nbn = N >> 7;
  const int m0 = (swz / nbn) << 7;
  const int n0 = (swz % nbn) << 7;
  const int wr = (w >> 1) << 6, wc = (w & 1) << 6;
  const int l15 = lane & 15, lg = lane >> 4;
  // staging: thread covers rows (tid>>2) and 64+(tid>>2); 4 slots/row of 16B.
  // source slot pre-swizzled with sigma(row) = ((row>>1)&3) (involution w/ read)
  const int srow = tid >> 2;
  const int sslot = (tid & 3) ^ ((tid >> 3) & 3);
  const u16* Ag = A  + (size_t)(m0 + srow) * K + sslot * 8;
  const u16* Bg = Bt + (size_t)(n0 + srow) * K + sslot * 8;

  f32x4 acc[4][4];
#pragma unroll
  for (int i = 0; i < 4; ++i)
#pragma unroll
    for (int j = 0; j < 4; ++j) acc[i][j] = f32x4{0.f, 0.f, 0.f, 0.f};

  // prologue: stage tile 0
#pragma unroll
  for (int j = 0; j < 2; ++j) {
    load_lds16(Ag + (size_t)(j * 64) * K, (const char*)As[0] + j * 4096 + tid * 16);
    load_lds16(Bg + (size_t)(j * 64) * K, (const char*)Bs[0] + j * 4096 + tid * 16);
  }
  __syncthreads();

  for (int kt = 0; kt < K; kt += 32) {
    const int buf = (kt >> 5) & 1;
    if (kt + 32 < K) {  // issue next tile's loads BEFORE compute (uniform branch)
#pragma unroll
      for (int j = 0; j < 2; ++j) {
        load_lds16(Ag + (size_t)(j * 64) * K + kt + 32, (const char*)As[buf ^ 1] + j * 4096 + tid * 16);
        load_lds16(Bg + (size_t)(j * 64) * K + kt + 32, (const char*)Bs[buf ^ 1] + j * 4096 + tid * 16);
      }
    }
    bf16x8 af[4], bfr[4];
#pragma unroll
    for (int i = 0; i < 4; ++i) {
      const int ra = wr + i * 16 + l15;
      const int rb = wc + i * 16 + l15;
      af[i]  = *reinterpret_cast<const bf16x8*>(As[buf] + ra * 32 + ((lg ^ ((ra >> 1) & 3)) << 3));
      bfr[i] = *reinterpret_cast<const bf16x8*>(Bs[buf] + rb * 32 + ((lg ^ ((rb >> 1) & 3)) << 3));
    }
#pragma unroll
    for (int mi = 0; mi < 4; ++mi)
#pragma unroll
      for (int ni = 0; ni < 4; ++ni)
        acc[mi][ni] = __builtin_amdgcn_mfma_f32_16x16x32_bf16(af[mi], bfr[ni], acc[mi][ni], 0, 0, 0);
    __syncthreads();  // drains vmcnt: staged tile ready; buf safe to overwrite
  }

  const int orow0 = m0 + wr + lg * 4;
  const int ocol0 = n0 + wc + l15;
  if (mode == 1) {
    float* C = (float*)P.g[blockIdx.z].C;
#pragma unroll
    for (int ni = 0; ni < 4; ++ni) {
      float bv = bias ? bias[ocol0 + ni * 16] : 0.f;
#pragma unroll
      for (int mi = 0; mi < 4; ++mi)
#pragma unroll
        for (int r = 0; r < 4; ++r)
          C[(size_t)(orow0 + mi * 16 + r) * N + ocol0 + ni * 16] = acc[mi][ni][r] + bv;
    }
  } else if (mode == 2) {
    // vT[bh][d][kk]: 128-row tile never straddles a batch boundary
    u16* C = (u16*)P.g[blockIdx.z].C;
    const int b = m0 >> 10;
    const int kk0 = (orow0 & 1023);
#pragma unroll
    for (int ni = 0; ni < 4; ++ni) {
      const int col = ocol0 + ni * 16;
      const int hh = col >> 6, d = col & 63;
      u16* vbase = C + ((size_t)(b * 16 + hh)) * 65536 + d * 1024 + kk0;
#pragma unroll
      for (int mi = 0; mi < 4; ++mi) {
        u16x4 pv;
#pragma unroll
        for (int r = 0; r < 4; ++r) pv[r] = f2bf(acc[mi][ni][r] * sc);
        *reinterpret_cast<u16x4*>(vbase + mi * 16) = pv;
      }
    }
  } else {
    u16* C = (u16*)P.g[blockIdx.z].C;
#pragma unroll
    for (int ni = 0; ni < 4; ++ni)
#pragma unroll
      for (int mi = 0; mi < 4; ++mi)
#pragma unroll
        for (int r = 0; r < 4; ++r)
          C[(size_t)(orow0 + mi * 16 + r) * N + ocol0 + ni * 16] = f2bf(acc[mi][ni][r] * sc);
  }
}

// ---------------- pass1: l[k] = sum_q exp2(s[q,k])  (q pre-scaled by SC2) ----
// QBLK=64 cooperative Q staging (dbuf, issue-early, G21 swizzle); XCD-chunked
// 1D grid swizzle (all kb-blocks of a bh on one XCD).
__global__ __launch_bounds__(256) void k_pass1(const u16* __restrict__ q_all,
                                               const u16* __restrict__ k_all,
                                               float* __restrict__ l_buf) {
  const int bid = blockIdx.x;
  const int swz = (bid & 7) * 128 + (bid >> 3);
  const int bh = swz >> 3, kb = swz & 7;
  const int b = bh >> 4, h = bh & 15;
  __shared__ u16 Qs[2][4096];  // [buf][64 q rows x 64 dims], swizzled
  const int t = threadIdx.x;
  const int lane = t & 63, w = t >> 6;
  const int l15 = lane & 15, lg = lane >> 4;
  const u16* qp = q_all + (size_t)b * 1048576 + h * 64;
  const u16* kp = k_all + (size_t)b * 1048576 + h * 64;
  const int kc0 = kb * 128 + w * 32;

  bf16x8 bfr[2][2];
#pragma unroll
  for (int c = 0; c < 2; ++c)
#pragma unroll
    for (int ks = 0; ks < 2; ++ks)
      bfr[c][ks] = *reinterpret_cast<const bf16x8*>(
          kp + (size_t)(kc0 + c * 16 + l15) * 1024 + ks * 32 + lg * 8);

  const int qrow = t >> 3, qslot = (t & 7) ^ (qrow & 7);
  const u16* qg = qp + (size_t)qrow * 1024 + (qslot << 3);

#pragma unroll
  for (int j = 0; j < 2; ++j)
    load_lds16(qg + (size_t)(j * 32) * 1024, (const char*)&Qs[0][0] + j * 4096 + t * 16);
  __syncthreads();

  float acc0 = 0.f, acc1 = 0.f;
  const int qsw = l15 & 7;

#pragma unroll 1
  for (int qt = 0; qt < 1024; qt += 64) {
    const int buf = (qt >> 6) & 1;
    if (qt + 64 < 1024) {
#pragma unroll
      for (int j = 0; j < 2; ++j)
        load_lds16(qg + (size_t)(qt + 64 + j * 32) * 1024,
                   (const char*)&Qs[buf ^ 1][0] + j * 4096 + t * 16);
    }
    const u16* Qb = Qs[buf];
#pragma unroll
    for (int qf = 0; qf < 4; ++qf) {
      bf16x8 a0 = *reinterpret_cast<const bf16x8*>(Qb + (qf * 16 + l15) * 64 + ((lg ^ qsw) << 3));
      bf16x8 a1 = *reinterpret_cast<const bf16x8*>(Qb + (qf * 16 + l15) * 64 + (((4 + lg) ^ qsw) << 3));
#pragma unroll
      for (int c = 0; c < 2; ++c) {
        f32x4 z = {0.f, 0.f, 0.f, 0.f};
        f32x4 s = __builtin_amdgcn_mfma_f32_16x16x32_bf16(a0, bfr[c][0], z, 0, 0, 0);
        s = __builtin_amdgcn_mfma_f32_16x16x32_bf16(a1, bfr[c][1], s, 0, 0, 0);
        float e = __builtin_amdgcn_exp2f(s[0]) + __builtin_amdgcn_exp2f(s[1])
                + __builtin_amdgcn_exp2f(s[2]) + __builtin_amdgcn_exp2f(s[3]);
        if (c) acc1 += e; else acc0 += e;
      }
    }
    __syncthreads();
  }
  acc0 += __shfl_xor(acc0, 16); acc0 += __shfl_xor(acc0, 32);
  acc1 += __shfl_xor(acc1, 16); acc1 += __shfl_xor(acc1, 32);
  if (lane < 32) {
    int col = kc0 + lane;
    l_buf[(size_t)bh * 1024 + col] = (lane < 16) ? acc0 : acc1;
  }
}

// ---------------- pass2: O[q,d] = sum_kk exp2(s - log2 l[kk]) * v[kk,d] ----------------
// 16x16 verified structure + cooperative LDS staging (dbuf K/V, issue-early,
// G21 swizzle). Normalizer folded as MFMA C-initializer. setprio around MFMA.
__global__ __launch_bounds__(256, 4) void k_pass2(const u16* __restrict__ q_all,
                                                  const u16* __restrict__ k_all,
                                                  const u16* __restrict__ vT,
                                                  const float* __restrict__ l_buf,
                                                  u16* __restrict__ o_all) {
  const int bid = blockIdx.x;
  const int swz = (bid & 7) * 128 + (bid >> 3);
  const int bh = swz >> 3, qb = swz & 7;
  const int b = bh >> 4, h = bh & 15;
  __shared__ u16 Ks[2][2048];              // [buf][32 keys x 64 dims], swizzled
  __shared__ u16 Vs[2][2048];              // [buf][64 d x 32 kk], swizzled
  __shared__ u16 p_lds[4][2][640];         // [wave][qfrag][16 q x 40 pitch]
  __shared__ float rl_lds[1024];           // -log2(l) per key
  const int t = threadIdx.x;
  const int lane = t & 63, w = t >> 6;
  const int l15 = lane & 15, lg = lane >> 4;
  const int q0 = qb * 128 + w * 32;
  const u16* qp = q_all + (size_t)b * 1048576 + h * 64;
  const u16* kp = k_all + (size_t)b * 1048576 + h * 64;
  const u16* vp = vT + (size_t)bh * 65536;

  // -log2(l) into LDS (once; covered by prologue barrier)
  {
    f32x4 lv = reinterpret_cast<const f32x4*>(l_buf + (size_t)bh * 1024)[t];
    f32x4 rv;
#pragma unroll
    for (int j = 0; j < 4; ++j) rv[j] = -__log2f(lv[j]);
    reinterpret_cast<f32x4*>(rl_lds)[t] = rv;
  }

  const int krow = t >> 3, kslot = (t & 7) ^ (krow & 7);
  const u16* kg = kp + (size_t)krow * 1024 + (kslot << 3);
  const int vrow = t >> 2, vslot = (t & 3) ^ (vrow & 3);
  const u16* vg = vp + (size_t)vrow * 1024 + (vslot << 3);

  bf16x8 bq[2][2];
#pragma unroll
  for (int qf = 0; qf < 2; ++qf)
#pragma unroll
    for (int s = 0; s < 2; ++s)
      bq[qf][s] = *reinterpret_cast<const bf16x8*>(
          qp + (size_t)(q0 + qf * 16 + l15) * 1024 + s * 32 + lg * 8);

  f32x4 od[2][4];
#pragma unroll
  for (int qf = 0; qf < 2; ++qf)
#pragma unroll
    for (int n = 0; n < 4; ++n) od[qf][n] = f32x4{0.f, 0.f, 0.f, 0.f};

  // prologue: stage tile 0
  load_lds16(kg, (const char*)&Ks[0][0] + t * 16);
  load_lds16(vg, (const char*)&Vs[0][0] + t * 16);
  __syncthreads();

  const int ksw = l15 & 7, vsw = l15 & 3;

#pragma unroll 1
  for (int kt = 0; kt < 1024; kt += 32) {
    const int buf = (kt >> 5) & 1;
    if (kt + 32 < 1024) {
      load_lds16(kg + (size_t)(kt + 32) * 1024, (const char*)&Ks[buf ^ 1][0] + t * 16);
      load_lds16(vg + (kt + 32), (const char*)&Vs[buf ^ 1][0] + t * 16);
    }
    const u16* Kb = Ks[buf];
    const u16* Vb = Vs[buf];
    bf16x8 k00 = *reinterpret_cast<const bf16x8*>(Kb + l15 * 64 + ((lg ^ ksw) << 3));
    bf16x8 k01 = *reinterpret_cast<const bf16x8*>(Kb + l15 * 64 + (((4 + lg) ^ ksw) << 3));
    bf16x8 k10 = *reinterpret_cast<const bf16x8*>(Kb + (16 + l15) * 64 + ((lg ^ ksw) << 3));
    bf16x8 k11 = *reinterpret_cast<const bf16x8*>(Kb + (16 + l15) * 64 + (((4 + lg) ^ ksw) << 3));
    bf16x8 vc[4];
#pragma unroll
    for (int n = 0; n < 4; ++n)
      vc[n] = *reinterpret_cast<const bf16x8*>(Vb + (n * 16 + l15) * 32 + ((lg ^ vsw) << 3));

    // per-lane key bias -log2(l) (broadcast within 16-lane groups)
    f32x4 b0 = *reinterpret_cast<const f32x4*>(&rl_lds[kt + lg * 4]);
    f32x4 b1 = *reinterpret_cast<const f32x4*>(&rl_lds[kt + 16 + lg * 4]);

    u16* pl = p_lds[w][0];
    u16* ph = p_lds[w][1];
#pragma unroll
    for (int qf = 0; qf < 2; ++qf) {
      __builtin_amdgcn_s_setprio(1);
      f32x4 s0 = __builtin_amdgcn_mfma_f32_16x16x32_bf16(k00, bq[qf][0], b0, 0, 0, 0);
      s0 = __builtin_amdgcn_mfma_f32_16x16x32_bf16(k01, bq[qf][1], s0, 0, 0, 0);
      f32x4 s1 = __builtin_amdgcn_mfma_f32_16x16x32_bf16(k10, bq[qf][0], b1, 0, 0, 0);
      s1 = __builtin_amdgcn_mfma_f32_16x16x32_bf16(k11, bq[qf][1], s1, 0, 0, 0);
      __builtin_amdgcn_s_setprio(0);
      u32x2 wlo, whi;
      wlo[0] = cvt_pk(__builtin_amdgcn_exp2f(s0[0]), __builtin_amdgcn_exp2f(s0[1]));
      wlo[1] = cvt_pk(__builtin_amdgcn_exp2f(s0[2]), __builtin_amdgcn_exp2f(s0[3]));
      whi[0] = cvt_pk(__builtin_amdgcn_exp2f(s1[0]), __builtin_amdgcn_exp2f(s1[1]));
      whi[1] = cvt_pk(__builtin_amdgcn_exp2f(s1[2]), __builtin_amdgcn_exp2f(s1[3]));
      u16* dst = qf ? ph : pl;
      *reinterpret_cast<u32x2*>(dst + l15 * 40 + lg * 4) = wlo;
      *reinterpret_cast<u32x2*>(dst + l15 * 40 + 16 + lg * 4) = whi;
    }
    bf16x8 pa0 = *reinterpret_cast<const bf16x8*>(pl + l15 * 40 + lg * 8);
    bf16x8 pa1 = *reinterpret_cast<const bf16x8*>(ph + l15 * 40 + lg * 8);
    __builtin_amdgcn_s_setprio(1);
#pragma unroll
    for (int n = 0; n < 4; ++n) {
      od[0][n] = __builtin_amdgcn_mfma_f32_16x16x32_bf16(pa0, vc[n], od[0][n], 0, 0, 0);
      od[1][n] = __builtin_amdgcn_mfma_f32_16x16x32_bf16(pa1, vc[n], od[1][n], 0, 0, 0);
    }
    __builtin_amdgcn_s_setprio(0);
    __syncthreads();  // drains staged loads (issued a full compute-phase ago)
  }

  u16* op = o_all + (size_t)b * 1048576 + h * 64;
#pragma unroll
  for (int qf = 0; qf < 2; ++qf)
#pragma unroll
    for (int n = 0; n < 4; ++n)
#pragma unroll
      for (int r = 0; r < 4; ++r)
        op[(size_t)(q0 + qf * 16 + lg * 4 + r) * 1024 + n * 16 + l15] = f2bf(od[qf][n][r]);
}

// ---------------- launch ----------------
extern "C" void kernel_launch(void* const* d_in, const int* in_sizes, int n_in,
                              void* d_out, int out_size, void* d_ws, size_t ws_size,
                              hipStream_t stream) {
  (void)in_sizes; (void)n_in; (void)out_size; (void)ws_size;
  char* base = (char*)d_ws;
  size_t off = 0;
  auto alloc = [&](size_t bytes) -> char* {
    char* p = base + off;
    off = (off + bytes + 255) & ~(size_t)255;
    return p;
  };
  u16* src_bf = (u16*)alloc(8ull * 1024 * 1024 * 2);
  u16* tgt_bf = (u16*)alloc(8ull * 1024 * 1024 * 2);
  u16* wq_bf  = (u16*)alloc(1024 * 1024 * 2);
  u16* wk_bf  = (u16*)alloc(1024 * 1024 * 2);
  u16* wv_bf  = (u16*)alloc(1024 * 1024 * 2);
  u16* WQt    = (u16*)alloc(1024 * 1024 * 2);
  u16* WKt    = (u16*)alloc(1024 * 1024 * 2);
  u16* WVt    = (u16*)alloc(1024 * 1024 * 2);
  u16* CqT    = (u16*)alloc(1024 * 1024 * 2);
  u16* CkT    = (u16*)alloc(1024 * 1024 * 2);
  u16* CvT    = (u16*)alloc(1024 * 1024 * 2);
  u16* owT    = (u16*)alloc(1024 * 1024 * 2);
  u16* q_all  = (u16*)alloc(8ull * 1024 * 1024 * 2);
  u16* k_all  = (u16*)alloc(8ull * 1024 * 1024 * 2);
  u16* vT     = (u16*)alloc(8ull * 1024 * 1024 * 2);
  u16* o_all  = (u16*)alloc(8ull * 1024 * 1024 * 2);
  float* l_buf = (float*)alloc(128 * 1024 * 4);

  Prep prep = {
    (const float*)d_in[0], (const float*)d_in[1],
    {(const float*)d_in[2], (const float*)d_in[3], (const float*)d_in[4]},
    {(const float*)d_in[5], (const float*)d_in[6], (const float*)d_in[7]},
    (const float*)d_in[8],
    src_bf, tgt_bf, {wq_bf, wk_bf, wv_bf}, {WQt, WKt, WVt}, owT
  };
  k_prep<<<20480, 256, 0, stream>>>(prep);

  // Combined projection weights; Cq carries SCALE*log2(e) so passes use raw exp2
  Gemm3 comb = {{{WQt, wq_bf, CqT, SC2, 0}, {WKt, wk_bf, CkT, 1.f, 0}, {WVt, wv_bf, CvT, 1.f, 0}}};
  k_gemm_bt<<<dim3(64, 1, 3), 256, 0, stream>>>(comb, 1024, 1024, nullptr);

  // q_all = src@Cq, k_all = tgt@Ck; V written directly transposed (mode 2)
  Gemm3 proj = {{{src_bf, CqT, q_all, 1.f, 0}, {tgt_bf, CkT, k_all, 1.f, 0}, {tgt_bf, CvT, vT, 1.f, 2}}};
  k_gemm_bt<<<dim3(512, 1, 3), 256, 0, stream>>>(proj, 1024, 1024, nullptr);

  k_pass1<<<1024, 256, 0, stream>>>(q_all, k_all, l_buf);
  k_pass2<<<1024, 256, 0, stream>>>(q_all, k_all, vT, l_buf, o_all);

  Gemm3 fin = {{{o_all, owT, d_out, 1.f, 1}, {o_all, owT, d_out, 1.f, 1}, {o_all, owT, d_out, 1.f, 1}}};
  k_gemm_bt<<<dim3(512, 1, 1), 256, 0, stream>>>(fin, 1024, 1024, (const float*)d_in[9]);
}

// Round 14
// 204.085 us; speedup vs baseline: 1.0406x; 1.0406x over previous
//
#include <hip/hip_runtime.h>

using u16 = unsigned short;
typedef float f32x4 __attribute__((ext_vector_type(4)));
typedef __bf16 bf16x8 __attribute__((ext_vector_type(8)));
typedef unsigned short u16x4 __attribute__((ext_vector_type(4)));
typedef unsigned short u16x8 __attribute__((ext_vector_type(8)));
typedef unsigned int u32x2 __attribute__((ext_vector_type(2)));

static constexpr float SC2 = 0.03125f * 1.44269504088896f; // (1/sqrt(1024)) * log2(e)

static __device__ __forceinline__ u16 f2bf(float f) {
  unsigned u = __builtin_bit_cast(unsigned, f);
  u += 0x7FFFu + ((u >> 16) & 1u);
  return (u16)(u >> 16);
}
static __device__ __forceinline__ float bf2f(u16 h) {
  unsigned u = ((unsigned)h) << 16;
  return __builtin_bit_cast(float, u);
}
static __device__ __forceinline__ unsigned cvt_pk(float lo, float hi) {
  unsigned r;
  asm("v_cvt_pk_bf16_f32 %0, %1, %2" : "=v"(r) : "v"(lo), "v"(hi));
  return r;
}

typedef __attribute__((address_space(3))) unsigned int lds_uint;
typedef __attribute__((address_space(1))) unsigned int g_uint;

static __device__ __forceinline__ void load_lds16(const u16* gp, const void* lp) {
  __builtin_amdgcn_global_load_lds((g_uint*)(unsigned long long)gp,
                                   (lds_uint*)(unsigned int)(unsigned long long)lp,
                                   16, 0, 0);
}

// ---------------- fused prep: casts + LDS-transpose relayouts, ONE dispatch ----------------
// block ranges: [0,16384) src/tgt cast; [16384,19456) w casts;
// [19456,20224) W 64x64 tile-transposes; [20224,20480) owT tile-transposes.
struct Prep {
  const float* src; const float* tgt;
  const float* w[3]; const float* W[3]; const float* ow;
  u16* src_bf; u16* tgt_bf; u16* w_bf[3]; u16* Wt[3]; u16* owT;
};
__global__ __launch_bounds__(256) void k_prep(Prep P) {
  __shared__ float tile[64][65];
  const int bid = blockIdx.x, t = threadIdx.x;
  if (bid < 16384) {
    const float* in = bid < 8192 ? P.src : P.tgt;
    u16* out = bid < 8192 ? P.src_bf : P.tgt_bf;
    int i = (bid & 8191) * 256 + t;
    f32x4 v = reinterpret_cast<const f32x4*>(in)[i];
    u16x4 o;
    o[0] = f2bf(v[0]); o[1] = f2bf(v[1]); o[2] = f2bf(v[2]); o[3] = f2bf(v[3]);
    reinterpret_cast<u16x4*>(out)[i] = o;
  } else if (bid < 19456) {
    int r = bid - 16384;
    int z = r >> 10;
    int i = (r & 1023) * 256 + t;
    f32x4 v = reinterpret_cast<const f32x4*>(P.w[z])[i];
    u16x4 o;
    o[0] = f2bf(v[0]); o[1] = f2bf(v[1]); o[2] = f2bf(v[2]); o[3] = f2bf(v[3]);
    reinterpret_cast<u16x4*>(P.w_bf[z])[i] = o;
  } else if (bid < 20224) {
    // W (H,1024,64) -> WQt[h*64+j][c]; 64x64 tile at (h, c0): contiguous 16KB read
    int r = bid - 19456;
    int z = r >> 8;
    int rr = r & 255;
    int h = rr >> 4, c0 = (rr & 15) << 6;
    const float* Wt_in = P.W[z] + (size_t)h * 65536 + (size_t)c0 * 64;
#pragma unroll
    for (int rep = 0; rep < 4; ++rep) {
      int i = rep * 256 + t;
      int cc = i >> 4, j4 = (i & 15) * 4;
      f32x4 v = *reinterpret_cast<const f32x4*>(Wt_in + cc * 64 + j4);
#pragma unroll
      for (int q = 0; q < 4; ++q) tile[cc][j4 + q] = v[q];
    }
    __syncthreads();
    u16* out = P.Wt[z];
#pragma unroll
    for (int rep = 0; rep < 2; ++rep) {
      int i = rep * 256 + t;
      int j = i >> 3, cc8 = (i & 7) * 8;
      u16x8 o;
#pragma unroll
      for (int q = 0; q < 8; ++q) o[q] = f2bf(tile[cc8 + q][j]);
      *reinterpret_cast<u16x8*>(out + (size_t)(h * 64 + j) * 1024 + c0 + cc8) = o;
    }
  } else {
    // ow (1024,1024) -> owT[n][k] = ow[k][n]; 64x64 tile at (k0, n0)
    int r = bid - 20224;
    int k0 = (r >> 4) << 6, n0 = (r & 15) << 6;
#pragma unroll
    for (int rep = 0; rep < 4; ++rep) {
      int i = rep * 256 + t;
      int kk = i >> 4, n4 = (i & 15) * 4;
      f32x4 v = *reinterpret_cast<const f32x4*>(P.ow + (size_t)(k0 + kk) * 1024 + n0 + n4);
#pragma unroll
      for (int q = 0; q < 4; ++q) tile[kk][n4 + q] = v[q];
    }
    __syncthreads();
#pragma unroll
    for (int rep = 0; rep < 2; ++rep) {
      int i = rep * 256 + t;
      int nn = i >> 3, kk8 = (i & 7) * 8;
      u16x8 o;
#pragma unroll
      for (int q = 0; q < 8; ++q) o[q] = f2bf(tile[kk8 + q][nn]);
      *reinterpret_cast<u16x8*>(P.owT + (size_t)(n0 + nn) * 1024 + k0 + kk8) = o;
    }
  }
}

// ---------------- bf16 GEMM, C[m][n] = scale * sum_k A[m][k]*Bt[n][k] ----------------
// 128x128 tile, BK=64, 4 waves (2x2). XCD-bijective block swizzle (T1).
// G21 both-sides XOR swizzle on LDS. Issue-early double-buffered staging.
// mode 0: bf16 C[m][n]; mode 1: f32 C + bias; mode 2: bf16 vT[bh][d][kk].
// NOTE (R13 post-mortem): BK=32 variant measured SLOWER (73.6 vs 64.5 us)
// despite higher occupancy -- barrier amortization dominates here. Keep BK=64.
struct GemmPtrs { const u16* A; const u16* B; void* C; float scale; int mode; };
struct Gemm3 { GemmPtrs g[3]; };

__global__ __launch_bounds__(256) void k_gemm_bt(Gemm3 P, int N, int K,
                                                 const float* __restrict__ bias) {
  const u16* A  = P.g[blockIdx.z].A;
  const u16* Bt = P.g[blockIdx.z].B;
  const float sc = P.g[blockIdx.z].scale;
  const int mode = P.g[blockIdx.z].mode;
  __shared__ u16 As[2][128 * 64];
  __shared__ u16 Bs[2][128 * 64];
  const int tid = threadIdx.x, lane = tid & 63, w = tid >> 6;
  const int swz = (blockIdx.x & 7) * (gridDim.x >> 3) + (blockIdx.x >> 3);
  const int nbn = N >> 7;
  const int m0 = (swz / nbn) << 7;
  const int n0 = (swz % nbn) << 7;
  const int wr = (w >> 1) << 6, wc = (w & 1) << 6;
  const int l15 = lane & 15, lg = lane >> 4;
  const int srow = tid >> 3;
  const int sslot = (tid & 7) ^ (srow & 7);
  const u16* Ag = A  + (size_t)(m0 + srow) * K + sslot * 8;
  const u16* Bg = Bt + (size_t)(n0 + srow) * K + sslot * 8;

  f32x4 acc[4][4];
#pragma unroll
  for (int i = 0; i < 4; ++i)
#pragma unroll
    for (int j = 0; j < 4; ++j) acc[i][j] = f32x4{0.f, 0.f, 0.f, 0.f};

  // prologue: stage tile 0
#pragma unroll
  for (int j = 0; j < 4; ++j) {
    load_lds16(Ag + (size_t)(j * 32) * K, (const char*)As[0] + j * 4096 + tid * 16);
    load_lds16(Bg + (size_t)(j * 32) * K, (const char*)Bs[0] + j * 4096 + tid * 16);
  }
  __syncthreads();

  for (int kt = 0; kt < K; kt += 64) {
    const int buf = (kt >> 6) & 1;
    if (kt + 64 < K) {  // issue next tile's loads BEFORE compute (uniform branch)
#pragma unroll
      for (int j = 0; j < 4; ++j) {
        load_lds16(Ag + (size_t)(j * 32) * K + kt + 64, (const char*)As[buf ^ 1] + j * 4096 + tid * 16);
        load_lds16(Bg + (size_t)(j * 32) * K + kt + 64, (const char*)Bs[buf ^ 1] + j * 4096 + tid * 16);
      }
    }
#pragma unroll
    for (int kh = 0; kh < 2; ++kh) {
      bf16x8 af[4], bfr[4];
#pragma unroll
      for (int i = 0; i < 4; ++i) {
        const int ra = wr + i * 16 + l15;
        const int rb = wc + i * 16 + l15;
        af[i]  = *reinterpret_cast<const bf16x8*>(As[buf] + ra * 64 + ((((kh << 2) | lg) ^ (ra & 7)) << 3));
        bfr[i] = *reinterpret_cast<const bf16x8*>(Bs[buf] + rb * 64 + ((((kh << 2) | lg) ^ (rb & 7)) << 3));
      }
#pragma unroll
      for (int mi = 0; mi < 4; ++mi)
#pragma unroll
        for (int ni = 0; ni < 4; ++ni)
          acc[mi][ni] = __builtin_amdgcn_mfma_f32_16x16x32_bf16(af[mi], bfr[ni], acc[mi][ni], 0, 0, 0);
    }
    __syncthreads();  // drains vmcnt: staged tile ready; buf safe to overwrite
  }

  const int orow0 = m0 + wr + lg * 4;
  const int ocol0 = n0 + wc + l15;
  if (mode == 1) {
    float* C = (float*)P.g[blockIdx.z].C;
#pragma unroll
    for (int ni = 0; ni < 4; ++ni) {
      float bv = bias ? bias[ocol0 + ni * 16] : 0.f;
#pragma unroll
      for (int mi = 0; mi < 4; ++mi)
#pragma unroll
        for (int r = 0; r < 4; ++r)
          C[(size_t)(orow0 + mi * 16 + r) * N + ocol0 + ni * 16] = acc[mi][ni][r] + bv;
    }
  } else if (mode == 2) {
    // vT[bh][d][kk]: 128-row tile never straddles a batch boundary
    u16* C = (u16*)P.g[blockIdx.z].C;
    const int b = m0 >> 10;
    const int kk0 = (orow0 & 1023);
#pragma unroll
    for (int ni = 0; ni < 4; ++ni) {
      const int col = ocol0 + ni * 16;
      const int hh = col >> 6, d = col & 63;
      u16* vbase = C + ((size_t)(b * 16 + hh)) * 65536 + d * 1024 + kk0;
#pragma unroll
      for (int mi = 0; mi < 4; ++mi) {
        u16x4 pv;
#pragma unroll
        for (int r = 0; r < 4; ++r) pv[r] = f2bf(acc[mi][ni][r] * sc);
        *reinterpret_cast<u16x4*>(vbase + mi * 16) = pv;
      }
    }
  } else {
    u16* C = (u16*)P.g[blockIdx.z].C;
#pragma unroll
    for (int ni = 0; ni < 4; ++ni)
#pragma unroll
      for (int mi = 0; mi < 4; ++mi)
#pragma unroll
        for (int r = 0; r < 4; ++r)
          C[(size_t)(orow0 + mi * 16 + r) * N + ocol0 + ni * 16] = f2bf(acc[mi][ni][r] * sc);
  }
}

// ---------------- pass1: l[k] = sum_q exp2(s[q,k])  (q pre-scaled by SC2) ----
// QBLK=64 cooperative Q staging (dbuf, issue-early, G21 swizzle); XCD-chunked
// 1D grid swizzle (all kb-blocks of a bh on one XCD).
__global__ __launch_bounds__(256) void k_pass1(const u16* __restrict__ q_all,
                                               const u16* __restrict__ k_all,
                                               float* __restrict__ l_buf) {
  const int bid = blockIdx.x;
  const int swz = (bid & 7) * 128 + (bid >> 3);
  const int bh = swz >> 3, kb = swz & 7;
  const int b = bh >> 4, h = bh & 15;
  __shared__ u16 Qs[2][4096];  // [buf][64 q rows x 64 dims], swizzled
  const int t = threadIdx.x;
  const int lane = t & 63, w = t >> 6;
  const int l15 = lane & 15, lg = lane >> 4;
  const u16* qp = q_all + (size_t)b * 1048576 + h * 64;
  const u16* kp = k_all + (size_t)b * 1048576 + h * 64;
  const int kc0 = kb * 128 + w * 32;

  bf16x8 bfr[2][2];
#pragma unroll
  for (int c = 0; c < 2; ++c)
#pragma unroll
    for (int ks = 0; ks < 2; ++ks)
      bfr[c][ks] = *reinterpret_cast<const bf16x8*>(
          kp + (size_t)(kc0 + c * 16 + l15) * 1024 + ks * 32 + lg * 8);

  const int qrow = t >> 3, qslot = (t & 7) ^ (qrow & 7);
  const u16* qg = qp + (size_t)qrow * 1024 + (qslot << 3);

#pragma unroll
  for (int j = 0; j < 2; ++j)
    load_lds16(qg + (size_t)(j * 32) * 1024, (const char*)&Qs[0][0] + j * 4096 + t * 16);
  __syncthreads();

  float acc0 = 0.f, acc1 = 0.f;
  const int qsw = l15 & 7;

#pragma unroll 1
  for (int qt = 0; qt < 1024; qt += 64) {
    const int buf = (qt >> 6) & 1;
    if (qt + 64 < 1024) {
#pragma unroll
      for (int j = 0; j < 2; ++j)
        load_lds16(qg + (size_t)(qt + 64 + j * 32) * 1024,
                   (const char*)&Qs[buf ^ 1][0] + j * 4096 + t * 16);
    }
    const u16* Qb = Qs[buf];
#pragma unroll
    for (int qf = 0; qf < 4; ++qf) {
      bf16x8 a0 = *reinterpret_cast<const bf16x8*>(Qb + (qf * 16 + l15) * 64 + ((lg ^ qsw) << 3));
      bf16x8 a1 = *reinterpret_cast<const bf16x8*>(Qb + (qf * 16 + l15) * 64 + (((4 + lg) ^ qsw) << 3));
#pragma unroll
      for (int c = 0; c < 2; ++c) {
        f32x4 z = {0.f, 0.f, 0.f, 0.f};
        f32x4 s = __builtin_amdgcn_mfma_f32_16x16x32_bf16(a0, bfr[c][0], z, 0, 0, 0);
        s = __builtin_amdgcn_mfma_f32_16x16x32_bf16(a1, bfr[c][1], s, 0, 0, 0);
        float e = __builtin_amdgcn_exp2f(s[0]) + __builtin_amdgcn_exp2f(s[1])
                + __builtin_amdgcn_exp2f(s[2]) + __builtin_amdgcn_exp2f(s[3]);
        if (c) acc1 += e; else acc0 += e;
      }
    }
    __syncthreads();
  }
  acc0 += __shfl_xor(acc0, 16); acc0 += __shfl_xor(acc0, 32);
  acc1 += __shfl_xor(acc1, 16); acc1 += __shfl_xor(acc1, 32);
  if (lane < 32) {
    int col = kc0 + lane;
    l_buf[(size_t)bh * 1024 + col] = (lane < 16) ? acc0 : acc1;
  }
}

// ---------------- pass2: O[q,d] = sum_kk exp2(s - log2 l[kk]) * v[kk,d] ----------------
// 16x16 verified structure + cooperative LDS staging (dbuf K/V, issue-early,
// G21 swizzle). Normalizer folded as MFMA C-initializer. setprio around MFMA.
__global__ __launch_bounds__(256, 4) void k_pass2(const u16* __restrict__ q_all,
                                                  const u16* __restrict__ k_all,
                                                  const u16* __restrict__ vT,
                                                  const float* __restrict__ l_buf,
                                                  u16* __restrict__ o_all) {
  const int bid = blockIdx.x;
  const int swz = (bid & 7) * 128 + (bid >> 3);
  const int bh = swz >> 3, qb = swz & 7;
  const int b = bh >> 4, h = bh & 15;
  __shared__ u16 Ks[2][2048];              // [buf][32 keys x 64 dims], swizzled
  __shared__ u16 Vs[2][2048];              // [buf][64 d x 32 kk], swizzled
  __shared__ u16 p_lds[4][2][640];         // [wave][qfrag][16 q x 40 pitch]
  __shared__ float rl_lds[1024];           // -log2(l) per key
  const int t = threadIdx.x;
  const int lane = t & 63, w = t >> 6;
  const int l15 = lane & 15, lg = lane >> 4;
  const int q0 = qb * 128 + w * 32;
  const u16* qp = q_all + (size_t)b * 1048576 + h * 64;
  const u16* kp = k_all + (size_t)b * 1048576 + h * 64;
  const u16* vp = vT + (size_t)bh * 65536;

  // -log2(l) into LDS (once; covered by prologue barrier)
  {
    f32x4 lv = reinterpret_cast<const f32x4*>(l_buf + (size_t)bh * 1024)[t];
    f32x4 rv;
#pragma unroll
    for (int j = 0; j < 4; ++j) rv[j] = -__log2f(lv[j]);
    reinterpret_cast<f32x4*>(rl_lds)[t] = rv;
  }

  const int krow = t >> 3, kslot = (t & 7) ^ (krow & 7);
  const u16* kg = kp + (size_t)krow * 1024 + (kslot << 3);
  const int vrow = t >> 2, vslot = (t & 3) ^ (vrow & 3);
  const u16* vg = vp + (size_t)vrow * 1024 + (vslot << 3);

  bf16x8 bq[2][2];
#pragma unroll
  for (int qf = 0; qf < 2; ++qf)
#pragma unroll
    for (int s = 0; s < 2; ++s)
      bq[qf][s] = *reinterpret_cast<const bf16x8*>(
          qp + (size_t)(q0 + qf * 16 + l15) * 1024 + s * 32 + lg * 8);

  f32x4 od[2][4];
#pragma unroll
  for (int qf = 0; qf < 2; ++qf)
#pragma unroll
    for (int n = 0; n < 4; ++n) od[qf][n] = f32x4{0.f, 0.f, 0.f, 0.f};

  // prologue: stage tile 0
  load_lds16(kg, (const char*)&Ks[0][0] + t * 16);
  load_lds16(vg, (const char*)&Vs[0][0] + t * 16);
  __syncthreads();

  const int ksw = l15 & 7, vsw = l15 & 3;

#pragma unroll 1
  for (int kt = 0; kt < 1024; kt += 32) {
    const int buf = (kt >> 5) & 1;
    if (kt + 32 < 1024) {
      load_lds16(kg + (size_t)(kt + 32) * 1024, (const char*)&Ks[buf ^ 1][0] + t * 16);
      load_lds16(vg + (kt + 32), (const char*)&Vs[buf ^ 1][0] + t * 16);
    }
    const u16* Kb = Ks[buf];
    const u16* Vb = Vs[buf];
    bf16x8 k00 = *reinterpret_cast<const bf16x8*>(Kb + l15 * 64 + ((lg ^ ksw) << 3));
    bf16x8 k01 = *reinterpret_cast<const bf16x8*>(Kb + l15 * 64 + (((4 + lg) ^ ksw) << 3));
    bf16x8 k10 = *reinterpret_cast<const bf16x8*>(Kb + (16 + l15) * 64 + ((lg ^ ksw) << 3));
    bf16x8 k11 = *reinterpret_cast<const bf16x8*>(Kb + (16 + l15) * 64 + (((4 + lg) ^ ksw) << 3));
    bf16x8 vc[4];
#pragma unroll
    for (int n = 0; n < 4; ++n)
      vc[n] = *reinterpret_cast<const bf16x8*>(Vb + (n * 16 + l15) * 32 + ((lg ^ vsw) << 3));

    // per-lane key bias -log2(l) (broadcast within 16-lane groups)
    f32x4 b0 = *reinterpret_cast<const f32x4*>(&rl_lds[kt + lg * 4]);
    f32x4 b1 = *reinterpret_cast<const f32x4*>(&rl_lds[kt + 16 + lg * 4]);

    u16* pl = p_lds[w][0];
    u16* ph = p_lds[w][1];
#pragma unroll
    for (int qf = 0; qf < 2; ++qf) {
      __builtin_amdgcn_s_setprio(1);
      f32x4 s0 = __builtin_amdgcn_mfma_f32_16x16x32_bf16(k00, bq[qf][0], b0, 0, 0, 0);
      s0 = __builtin_amdgcn_mfma_f32_16x16x32_bf16(k01, bq[qf][1], s0, 0, 0, 0);
      f32x4 s1 = __builtin_amdgcn_mfma_f32_16x16x32_bf16(k10, bq[qf][0], b1, 0, 0, 0);
      s1 = __builtin_amdgcn_mfma_f32_16x16x32_bf16(k11, bq[qf][1], s1, 0, 0, 0);
      __builtin_amdgcn_s_setprio(0);
      u32x2 wlo, whi;
      wlo[0] = cvt_pk(__builtin_amdgcn_exp2f(s0[0]), __builtin_amdgcn_exp2f(s0[1]));
      wlo[1] = cvt_pk(__builtin_amdgcn_exp2f(s0[2]), __builtin_amdgcn_exp2f(s0[3]));
      whi[0] = cvt_pk(__builtin_amdgcn_exp2f(s1[0]), __builtin_amdgcn_exp2f(s1[1]));
      whi[1] = cvt_pk(__builtin_amdgcn_exp2f(s1[2]), __builtin_amdgcn_exp2f(s1[3]));
      u16* dst = qf ? ph : pl;
      *reinterpret_cast<u32x2*>(dst + l15 * 40 + lg * 4) = wlo;
      *reinterpret_cast<u32x2*>(dst + l15 * 40 + 16 + lg * 4) = whi;
    }
    bf16x8 pa0 = *reinterpret_cast<const bf16x8*>(pl + l15 * 40 + lg * 8);
    bf16x8 pa1 = *reinterpret_cast<const bf16x8*>(ph + l15 * 40 + lg * 8);
    __builtin_amdgcn_s_setprio(1);
#pragma unroll
    for (int n = 0; n < 4; ++n) {
      od[0][n] = __builtin_amdgcn_mfma_f32_16x16x32_bf16(pa0, vc[n], od[0][n], 0, 0, 0);
      od[1][n] = __builtin_amdgcn_mfma_f32_16x16x32_bf16(pa1, vc[n], od[1][n], 0, 0, 0);
    }
    __builtin_amdgcn_s_setprio(0);
    __syncthreads();  // drains staged loads (issued a full compute-phase ago)
  }

  u16* op = o_all + (size_t)b * 1048576 + h * 64;
#pragma unroll
  for (int qf = 0; qf < 2; ++qf)
#pragma unroll
    for (int n = 0; n < 4; ++n)
#pragma unroll
      for (int r = 0; r < 4; ++r)
        op[(size_t)(q0 + qf * 16 + lg * 4 + r) * 1024 + n * 16 + l15] = f2bf(od[qf][n][r]);
}

// ---------------- launch ----------------
extern "C" void kernel_launch(void* const* d_in, const int* in_sizes, int n_in,
                              void* d_out, int out_size, void* d_ws, size_t ws_size,
                              hipStream_t stream) {
  (void)in_sizes; (void)n_in; (void)out_size; (void)ws_size;
  char* base = (char*)d_ws;
  size_t off = 0;
  auto alloc = [&](size_t bytes) -> char* {
    char* p = base + off;
    off = (off + bytes + 255) & ~(size_t)255;
    return p;
  };
  u16* src_bf = (u16*)alloc(8ull * 1024 * 1024 * 2);
  u16* tgt_bf = (u16*)alloc(8ull * 1024 * 1024 * 2);
  u16* wq_bf  = (u16*)alloc(1024 * 1024 * 2);
  u16* wk_bf  = (u16*)alloc(1024 * 1024 * 2);
  u16* wv_bf  = (u16*)alloc(1024 * 1024 * 2);
  u16* WQt    = (u16*)alloc(1024 * 1024 * 2);
  u16* WKt    = (u16*)alloc(1024 * 1024 * 2);
  u16* WVt    = (u16*)alloc(1024 * 1024 * 2);
  u16* CqT    = (u16*)alloc(1024 * 1024 * 2);
  u16* CkT    = (u16*)alloc(1024 * 1024 * 2);
  u16* CvT    = (u16*)alloc(1024 * 1024 * 2);
  u16* owT    = (u16*)alloc(1024 * 1024 * 2);
  u16* q_all  = (u16*)alloc(8ull * 1024 * 1024 * 2);
  u16* k_all  = (u16*)alloc(8ull * 1024 * 1024 * 2);
  u16* vT     = (u16*)alloc(8ull * 1024 * 1024 * 2);
  u16* o_all  = (u16*)alloc(8ull * 1024 * 1024 * 2);
  float* l_buf = (float*)alloc(128 * 1024 * 4);

  Prep prep = {
    (const float*)d_in[0], (const float*)d_in[1],
    {(const float*)d_in[2], (const float*)d_in[3], (const float*)d_in[4]},
    {(const float*)d_in[5], (const float*)d_in[6], (const float*)d_in[7]},
    (const float*)d_in[8],
    src_bf, tgt_bf, {wq_bf, wk_bf, wv_bf}, {WQt, WKt, WVt}, owT
  };
  k_prep<<<20480, 256, 0, stream>>>(prep);

  // Combined projection weights; Cq carries SCALE*log2(e) so passes use raw exp2
  Gemm3 comb = {{{WQt, wq_bf, CqT, SC2, 0}, {WKt, wk_bf, CkT, 1.f, 0}, {WVt, wv_bf, CvT, 1.f, 0}}};
  k_gemm_bt<<<dim3(64, 1, 3), 256, 0, stream>>>(comb, 1024, 1024, nullptr);

  // q_all = src@Cq, k_all = tgt@Ck; V written directly transposed (mode 2)
  Gemm3 proj = {{{src_bf, CqT, q_all, 1.f, 0}, {tgt_bf, CkT, k_all, 1.f, 0}, {tgt_bf, CvT, vT, 1.f, 2}}};
  k_gemm_bt<<<dim3(512, 1, 3), 256, 0, stream>>>(proj, 1024, 1024, nullptr);

  k_pass1<<<1024, 256, 0, stream>>>(q_all, k_all, l_buf);
  k_pass2<<<1024, 256, 0, stream>>>(q_all, k_all, vT, l_buf, o_all);

  Gemm3 fin = {{{o_all, owT, d_out, 1.f, 1}, {o_all, owT, d_out, 1.f, 1}, {o_all, owT, d_out, 1.f, 1}}};
  k_gemm_bt<<<dim3(512, 1, 1), 256, 0, stream>>>(fin, 1024, 1024, (const float*)d_in[9]);
}